// Round 4
// baseline (355.607 us; speedup 1.0000x reference)
//
#include <hip/hip_runtime.h>

// Causal flash attention fwd: B=4,H=16,S=2048,D=64. fp32 I/O, bf16 MFMA compute.
// MFMA 16x16x32 bf16. Layouts (HW-verified, learn_hip m89/m91/m120):
//   A[m=lane&15][k=quad*8+j], B[k=quad*8+j][n=lane&15],
//   C/D: col=lane&15, row=quad*4+reg.
// R8: OCCUPANCY. R7 at (256,3) used 148 regs -> 3 blocks/CU nominal, but the
// grid is exactly 4 blocks/CU -> two rounds [3 resident][1 resident], measured
// occupancy 20%: half the machine idle in round 2. Fix: fit 128 regs for
// (256,4) WITHOUT R6's spills by FUSING QK^T+softmax per-ct: each s[ct] (4
// regs) is consumed into exp2/pack right after its 2 MFMAs, so the 32-reg
// score arrays never materialize (R6 spilled because they did). Also fold
// SC_LOG2E into Q fragments at load (-32 v_mul/iter, same bf16 rel error).
// Retained from R7: shared K/V fragments (A+B q-tiles), raw-float4 prefetch
// with pack-in-STAGE, STAGE at iteration start (full-iteration latency
// coverage), swapped QK^T with in-register P (pi/sigma kv reorder), ONE
// barrier/tile, double-buffered K/V LDS, T5 setprio, complementary pairing.

typedef short bf16x4 __attribute__((ext_vector_type(4)));
typedef short bf16x8 __attribute__((ext_vector_type(8)));
typedef float f32x4  __attribute__((ext_vector_type(4)));

#define S_LEN 2048
#define D_DIM 64
#define BM 64
#define BN 64
#define KSTR 68
#define VSTR 68
#define SC_LOG2E 0.18033688011112042f   // (1/8) * log2(e), folded into Q frags

// pack two fp32 -> bf16x2 dword by truncation (1 v_perm_b32)
__device__ __forceinline__ unsigned pk2(float lo, float hi) {
    return __builtin_amdgcn_perm(__builtin_bit_cast(unsigned, hi),
                                 __builtin_bit_cast(unsigned, lo), 0x07060302u);
}

__device__ __forceinline__ bf16x8 ldfrag(const short* p) {
    bf16x4 lo = *(const bf16x4*)(p);
    bf16x4 hi = *(const bf16x4*)(p + 4);
    bf16x8 r;
    r[0] = lo[0]; r[1] = lo[1]; r[2] = lo[2]; r[3] = lo[3];
    r[4] = hi[0]; r[5] = hi[1]; r[6] = hi[2]; r[7] = hi[3];
    return r;
}

__device__ __forceinline__ bf16x8 mk8(unsigned u0, unsigned u1, unsigned u2, unsigned u3) {
    union { unsigned u[4]; bf16x8 v; } r;
    r.u[0] = u0; r.u[1] = u1; r.u[2] = u2; r.u[3] = u3;
    return r.v;
}

__global__ __launch_bounds__(256, 4) void fattn_kernel(
    const float* __restrict__ Q, const float* __restrict__ K,
    const float* __restrict__ V, float* __restrict__ O)
{
    __shared__ short Kl[2][BN * KSTR];        // 17408 B
    __shared__ short Vt[2][D_DIM * VSTR];     // 17408 B (V transposed [d][sigma(kv)])

    const int t    = threadIdx.x;
    const int wid  = t >> 6;
    const int lane = t & 63;
    const int quad = lane >> 4;
    const int lcol = lane & 15;

    // paired q-tiles: A = blockIdx.x (short), B = 31-blockIdx.x (long)
    const int na  = blockIdx.x + 1;           // 1..16
    const int nb  = 32 - blockIdx.x;          // 32..17  (nb > na always)
    const int q0a = blockIdx.x * BM;
    const int q0b = (31 - blockIdx.x) * BM;

    const int bh = blockIdx.y;
    const size_t base = (size_t)bh * (S_LEN * D_DIM);
    const float* Qh = Q + base;
    const float* Kh = K + base;
    const float* Vh = V + base;
    float*       Oh = O + base;

    // staging coordinates
    const int skv = t >> 2;            // K: row 0..63
    const int sd  = (t & 3) * 16;      // K: 16-col block
    const int vkv = (t & 31) * 2;      // V: row pair
    const int vdd = (t >> 5) * 8;      // V: 8-col block
    // sigma(kv): bit shuffle [c1 c0 Q1 Q0 r1 r0] -> [c1 Q1 Q0 c0 r1 r0]
    const int vkvp = (vkv & 0x23) | ((vkv & 0x0C) << 1) | ((vkv & 0x10) >> 2);

    // ---- Q fragments, PRE-SCALED by SC_LOG2E (exp2 input = raw QK dot) ----
    bf16x8 aqA0, aqA1, aqB0, aqB1;
    {
        const float* qp = Qh + (size_t)(q0a + wid * 16 + lcol) * D_DIM;
        float4 a = *(const float4*)(qp + quad * 8);
        float4 b = *(const float4*)(qp + quad * 8 + 4);
        float4 c = *(const float4*)(qp + 32 + quad * 8);
        float4 d = *(const float4*)(qp + 32 + quad * 8 + 4);
        aqA0 = mk8(pk2(a.x * SC_LOG2E, a.y * SC_LOG2E), pk2(a.z * SC_LOG2E, a.w * SC_LOG2E),
                   pk2(b.x * SC_LOG2E, b.y * SC_LOG2E), pk2(b.z * SC_LOG2E, b.w * SC_LOG2E));
        aqA1 = mk8(pk2(c.x * SC_LOG2E, c.y * SC_LOG2E), pk2(c.z * SC_LOG2E, c.w * SC_LOG2E),
                   pk2(d.x * SC_LOG2E, d.y * SC_LOG2E), pk2(d.z * SC_LOG2E, d.w * SC_LOG2E));
    }
    {
        const float* qp = Qh + (size_t)(q0b + wid * 16 + lcol) * D_DIM;
        float4 a = *(const float4*)(qp + quad * 8);
        float4 b = *(const float4*)(qp + quad * 8 + 4);
        float4 c = *(const float4*)(qp + 32 + quad * 8);
        float4 d = *(const float4*)(qp + 32 + quad * 8 + 4);
        aqB0 = mk8(pk2(a.x * SC_LOG2E, a.y * SC_LOG2E), pk2(a.z * SC_LOG2E, a.w * SC_LOG2E),
                   pk2(b.x * SC_LOG2E, b.y * SC_LOG2E), pk2(b.z * SC_LOG2E, b.w * SC_LOG2E));
        aqB1 = mk8(pk2(c.x * SC_LOG2E, c.y * SC_LOG2E), pk2(c.z * SC_LOG2E, c.w * SC_LOG2E),
                   pk2(d.x * SC_LOG2E, d.y * SC_LOG2E), pk2(d.z * SC_LOG2E, d.w * SC_LOG2E));
    }

    f32x4 oA[4], oB[4];
    #pragma unroll
    for (int nt = 0; nt < 4; ++nt) {
        oA[nt] = f32x4{0.f, 0.f, 0.f, 0.f};
        oB[nt] = f32x4{0.f, 0.f, 0.f, 0.f};
    }
    float lpA = 0.f, lpB = 0.f;        // per-lane row-sum for q = wid*16+lcol
    const int qrel  = wid * 16 + lcol; // q row this lane owns in softmax phase
    const int row_l = wid * 16 + quad * 4;  // q rows this lane owns in O

    // prefetch registers: RAW float4 (packed to bf16 only inside STAGE, one
    // full iteration after issue -> global latency fully covered by compute)
    float4 kr0, kr1, kr2, kr3, vr0, vr1, vr2, vr3;

#define PREFETCH(tl) do {                                                     \
        const float* kp_ = Kh + (size_t)((tl) * BN + skv) * D_DIM + sd;       \
        kr0 = *(const float4*)(kp_);     kr1 = *(const float4*)(kp_ + 4);     \
        kr2 = *(const float4*)(kp_ + 8); kr3 = *(const float4*)(kp_ + 12);    \
        const float* vp_ = Vh + (size_t)((tl) * BN + vkv) * D_DIM + vdd;      \
        vr0 = *(const float4*)(vp_);         vr1 = *(const float4*)(vp_ + 4); \
        vr2 = *(const float4*)(vp_ + D_DIM); vr3 = *(const float4*)(vp_ + D_DIM + 4); \
    } while (0)

#define STAGE(KB, VB) do {                                                    \
        short* kd_ = (KB) + skv * KSTR + sd;                                  \
        *(uint2*)(kd_)      = make_uint2(pk2(kr0.x, kr0.y), pk2(kr0.z, kr0.w)); \
        *(uint2*)(kd_ + 4)  = make_uint2(pk2(kr1.x, kr1.y), pk2(kr1.z, kr1.w)); \
        *(uint2*)(kd_ + 8)  = make_uint2(pk2(kr2.x, kr2.y), pk2(kr2.z, kr2.w)); \
        *(uint2*)(kd_ + 12) = make_uint2(pk2(kr3.x, kr3.y), pk2(kr3.z, kr3.w)); \
        short* vd_ = (VB) + vkvp;                                             \
        *(unsigned*)(vd_ + (vdd + 0) * VSTR) = pk2(vr0.x, vr2.x);             \
        *(unsigned*)(vd_ + (vdd + 1) * VSTR) = pk2(vr0.y, vr2.y);             \
        *(unsigned*)(vd_ + (vdd + 2) * VSTR) = pk2(vr0.z, vr2.z);             \
        *(unsigned*)(vd_ + (vdd + 3) * VSTR) = pk2(vr0.w, vr2.w);             \
        *(unsigned*)(vd_ + (vdd + 4) * VSTR) = pk2(vr1.x, vr3.x);             \
        *(unsigned*)(vd_ + (vdd + 5) * VSTR) = pk2(vr1.y, vr3.y);             \
        *(unsigned*)(vd_ + (vdd + 6) * VSTR) = pk2(vr1.z, vr3.z);             \
        *(unsigned*)(vd_ + (vdd + 7) * VSTR) = pk2(vr1.w, vr3.w);             \
    } while (0)

    // prologue: stage tile 0, issue prefetch of tile 1
    PREFETCH(0);
    STAGE(Kl[0], Vt[0]);
    PREFETCH(1);
    __syncthreads();

    for (int tile = 0; tile < nb; ++tile) {
        const int cur = tile & 1;
        const short* Kb = Kl[cur];
        const short* Vb = Vt[cur];
        const bool doA  = (tile < na);
        const bool diagB = (tile == nb - 1);
        const bool diagA = (tile == na - 1);

        // ---- stage NEXT tile first (prev barrier made cur^1 safe to write);
        //      ds_writes overlap the MFMA compute below; then issue prefetch
        //      for tile+2 (consumed at next iteration's STAGE) ----
        if (tile + 1 < nb) {
            STAGE(Kl[cur ^ 1], Vt[cur ^ 1]);
            if (tile + 2 < nb) PREFETCH(tile + 2);
        }

        // ---- FUSED swapped QK^T + softmax, per-ct: scores live 4 regs at a
        //      time; exp values packed straight into PV A-fragment words.
        //      lane holds e[ct][r] = P[q=lcol][16ct+4quad+r]; A-frag slot
        //      (h,j) needs P[q][pi(32h+8quad+j)] = e[2h+(j>>2)][j&3]. ----
        unsigned pbB[8], pbA[8];
        __builtin_amdgcn_s_setprio(1);
        #pragma unroll
        for (int ct = 0; ct < 4; ++ct) {
            const short* kp0 = &Kb[(ct * 16 + lcol) * KSTR + quad * 8];
            const bf16x8 b0 = ldfrag(kp0);        // d = quad*8+j       (k half 0)
            const bf16x8 b1 = ldfrag(kp0 + 32);   // d = 32+quad*8+j    (k half 1)
            f32x4 z = f32x4{0.f, 0.f, 0.f, 0.f};
            z = __builtin_amdgcn_mfma_f32_16x16x32_bf16(b0, aqB0, z, 0, 0, 0);
            z = __builtin_amdgcn_mfma_f32_16x16x32_bf16(b1, aqB1, z, 0, 0, 0);
            {
                float e0, e1, e2, e3;
                #pragma unroll
                for (int r = 0; r < 4; ++r) {
                    float x = z[r];
                    if (diagB && (ct * 16 + quad * 4 + r > qrel)) x = -__builtin_inff();
                    const float e = __builtin_amdgcn_exp2f(x);
                    lpB += e;
                    if (r == 0) e0 = e; else if (r == 1) e1 = e;
                    else if (r == 2) e2 = e; else e3 = e;
                }
                pbB[2 * ct]     = pk2(e0, e1);
                pbB[2 * ct + 1] = pk2(e2, e3);
            }
            if (doA) {
                f32x4 y = f32x4{0.f, 0.f, 0.f, 0.f};
                y = __builtin_amdgcn_mfma_f32_16x16x32_bf16(b0, aqA0, y, 0, 0, 0);
                y = __builtin_amdgcn_mfma_f32_16x16x32_bf16(b1, aqA1, y, 0, 0, 0);
                float e0, e1, e2, e3;
                #pragma unroll
                for (int r = 0; r < 4; ++r) {
                    float x = y[r];
                    if (diagA && (ct * 16 + quad * 4 + r > qrel)) x = -__builtin_inff();
                    const float e = __builtin_amdgcn_exp2f(x);
                    lpA += e;
                    if (r == 0) e0 = e; else if (r == 1) e1 = e;
                    else if (r == 2) e2 = e; else e3 = e;
                }
                pbA[2 * ct]     = pk2(e0, e1);
                pbA[2 * ct + 1] = pk2(e2, e3);
            }
        }
        const bf16x8 apB0 = mk8(pbB[0], pbB[1], pbB[2], pbB[3]);
        const bf16x8 apB1 = mk8(pbB[4], pbB[5], pbB[6], pbB[7]);
        bf16x8 apA0, apA1;
        if (doA) {
            apA0 = mk8(pbA[0], pbA[1], pbA[2], pbA[3]);
            apA1 = mk8(pbA[4], pbA[5], pbA[6], pbA[7]);
        }

        // ---- O += P V : V fragments shared A+B (sigma kv-slot order) ----
        #pragma unroll
        for (int nt = 0; nt < 4; ++nt) {
            const short* vp0 = &Vb[(nt * 16 + lcol) * VSTR + quad * 8];
            const bf16x8 v0 = ldfrag(vp0);
            const bf16x8 v1 = ldfrag(vp0 + 32);
            oB[nt] = __builtin_amdgcn_mfma_f32_16x16x32_bf16(apB0, v0, oB[nt], 0, 0, 0);
            oB[nt] = __builtin_amdgcn_mfma_f32_16x16x32_bf16(apB1, v1, oB[nt], 0, 0, 0);
            if (doA) {
                oA[nt] = __builtin_amdgcn_mfma_f32_16x16x32_bf16(apA0, v0, oA[nt], 0, 0, 0);
                oA[nt] = __builtin_amdgcn_mfma_f32_16x16x32_bf16(apA1, v1, oA[nt], 0, 0, 0);
            }
        }
        __builtin_amdgcn_s_setprio(0);

        __syncthreads();
    }

    // ---- epilogue: l lives per-lane for q=lcol; reduce across quads only ----
    lpA += __shfl_xor(lpA, 16, 64);
    lpA += __shfl_xor(lpA, 32, 64);
    lpB += __shfl_xor(lpB, 16, 64);
    lpB += __shfl_xor(lpB, 32, 64);
    #pragma unroll
    for (int r = 0; r < 4; ++r) {
        // O rows this lane stores are q = row_l + r; their l is held by lane
        // with lcol = quad*4+r (any quad after the reduce -> lane quad*4+r)
        const float invA = 1.0f / __shfl(lpA, quad * 4 + r, 64);
        const float invB = 1.0f / __shfl(lpB, quad * 4 + r, 64);
        float* opA = Oh + (size_t)(q0a + row_l + r) * D_DIM;
        float* opB = Oh + (size_t)(q0b + row_l + r) * D_DIM;
        #pragma unroll
        for (int nt = 0; nt < 4; ++nt) {
            opA[nt * 16 + lcol] = oA[nt][r] * invA;
            opB[nt * 16 + lcol] = oB[nt][r] * invB;
        }
    }
}

extern "C" void kernel_launch(void* const* d_in, const int* in_sizes, int n_in,
                              void* d_out, int out_size, void* d_ws, size_t ws_size,
                              hipStream_t stream) {
    const float* Q = (const float*)d_in[0];
    const float* K = (const float*)d_in[1];
    const float* V = (const float*)d_in[2];
    float*       O = (float*)d_out;
    dim3 grid(S_LEN / BM / 2, 4 * 16);   // 16 complementary q-pairs x 64 heads
    fattn_kernel<<<grid, 256, 0, stream>>>(Q, K, V, O);
}

// Round 5
// 232.778 us; speedup vs baseline: 1.5277x; 1.5277x over previous
//
#include <hip/hip_runtime.h>

// Causal flash attention fwd: B=4,H=16,S=2048,D=64. fp32 I/O, bf16 MFMA compute.
// MFMA 16x16x32 bf16. Layouts (HW-verified, learn_hip m89/m91/m120):
//   A[m=lane&15][k=quad*8+j], B[k=quad*8+j][n=lane&15],
//   C/D: col=lane&15, row=quad*4+reg.
// R9: SEQUENTIAL complementary pair. R8 proved the CONCURRENT pair (oA+oB=32
// AGPR + dual aq + dual pb) cannot fit 128 regs -> (256,4) spilled 12 dw/iter
// (WRITE 332 MB). R7 at (256,3) was spill-free but 1024 uniform blocks on
// 3-blocks/CU capacity -> rounds [3 resident][1 resident], occupancy 20%.
// Fix both with one lever: block processes q-tile B (32-i kv-tiles) THEN
// q-tile A (i+1) sequentially -> one tile live at a time (o=16, aq=8, pb=8),
// peak ~110 regs, spill-free at (256,4): whole grid resident in ONE round at
// 16 waves/CU, no tail. Cost: +35% logical KV traffic (A re-stages its own
// KV); LDS only ~30% busy and L3 (256MB) holds all KV (64MB). Head-clustering
// XCD swizzle (head = xcd*8 + r&7) keeps each XCD's 128 resident blocks on 8
// heads so same-head blocks stream the same KV tiles together (L2 reuse).
// Plus: lp tree-sum (serial chain 16 adds -> 4). Retained: swapped QK^T with
// in-register P (pi/sigma kv reorder, zero LDS for P), fused per-ct
// QK+softmax, pre-scaled Q (SC_LOG2E folded), raw-float4 prefetch with
// pack-in-STAGE, STAGE at iteration start, double-buffered K/V LDS, ONE
// barrier/tile, T5 setprio.

typedef short bf16x4 __attribute__((ext_vector_type(4)));
typedef short bf16x8 __attribute__((ext_vector_type(8)));
typedef float f32x4  __attribute__((ext_vector_type(4)));

#define S_LEN 2048
#define D_DIM 64
#define BM 64
#define BN 64
#define KSTR 68
#define VSTR 68
#define SC_LOG2E 0.18033688011112042f   // (1/8) * log2(e), folded into Q frags

// pack two fp32 -> bf16x2 dword by truncation (1 v_perm_b32)
__device__ __forceinline__ unsigned pk2(float lo, float hi) {
    return __builtin_amdgcn_perm(__builtin_bit_cast(unsigned, hi),
                                 __builtin_bit_cast(unsigned, lo), 0x07060302u);
}

__device__ __forceinline__ bf16x8 ldfrag(const short* p) {
    bf16x4 lo = *(const bf16x4*)(p);
    bf16x4 hi = *(const bf16x4*)(p + 4);
    bf16x8 r;
    r[0] = lo[0]; r[1] = lo[1]; r[2] = lo[2]; r[3] = lo[3];
    r[4] = hi[0]; r[5] = hi[1]; r[6] = hi[2]; r[7] = hi[3];
    return r;
}

__device__ __forceinline__ bf16x8 mk8(unsigned u0, unsigned u1, unsigned u2, unsigned u3) {
    union { unsigned u[4]; bf16x8 v; } r;
    r.u[0] = u0; r.u[1] = u1; r.u[2] = u2; r.u[3] = u3;
    return r.v;
}

__global__ __launch_bounds__(256, 4) void fattn_kernel(
    const float* __restrict__ Q, const float* __restrict__ K,
    const float* __restrict__ V, float* __restrict__ O)
{
    __shared__ short Kl[2][BN * KSTR];        // 17408 B
    __shared__ short Vt[2][D_DIM * VSTR];     // 17408 B (V transposed [d][sigma(kv)])

    const int t    = threadIdx.x;
    const int wid  = t >> 6;
    const int lane = t & 63;
    const int quad = lane >> 4;
    const int lcol = lane & 15;

    // ---- head-clustering XCD swizzle: flat = (r<<3)|xcd; XCD x (dispatch
    //      round-robin on flat%8) gets heads 8x..8x+7, all 16 pairs each ----
    const int flat = blockIdx.x;              // 0..1023
    const int xcd  = flat & 7;
    const int rr   = flat >> 3;               // 0..127
    const int bh   = xcd * 8 + (rr & 7);      // head 0..63
    const int ip   = rr >> 3;                 // pair index 0..15

    // complementary pair: B = long tile (32-ip kv-tiles), A = short (ip+1)
    const int ntb = 32 - ip;
    const int nta = ip + 1;
    const int q0b = (31 - ip) * BM;
    const int q0a = ip * BM;

    const size_t base = (size_t)bh * (S_LEN * D_DIM);
    const float* Qh = Q + base;
    const float* Kh = K + base;
    const float* Vh = V + base;
    float*       Oh = O + base;

    // staging coordinates
    const int skv = t >> 2;            // K: row 0..63
    const int sd  = (t & 3) * 16;      // K: 16-col block
    const int vkv = (t & 31) * 2;      // V: row pair
    const int vdd = (t >> 5) * 8;      // V: 8-col block
    // sigma(kv): bit shuffle [c1 c0 Q1 Q0 r1 r0] -> [c1 Q1 Q0 c0 r1 r0]
    const int vkvp = (vkv & 0x23) | ((vkv & 0x0C) << 1) | ((vkv & 0x10) >> 2);

    const int qrel  = wid * 16 + lcol;      // q row this lane owns in softmax
    const int row_l = wid * 16 + quad * 4;  // q rows this lane owns in O

    // prefetch registers: RAW float4 (packed to bf16 only inside STAGE, one
    // full iteration after issue -> global latency fully covered by compute)
    float4 kr0, kr1, kr2, kr3, vr0, vr1, vr2, vr3;

#define PREFETCH(tl) do {                                                     \
        const float* kp_ = Kh + (size_t)((tl) * BN + skv) * D_DIM + sd;       \
        kr0 = *(const float4*)(kp_);     kr1 = *(const float4*)(kp_ + 4);     \
        kr2 = *(const float4*)(kp_ + 8); kr3 = *(const float4*)(kp_ + 12);    \
        const float* vp_ = Vh + (size_t)((tl) * BN + vkv) * D_DIM + vdd;      \
        vr0 = *(const float4*)(vp_);         vr1 = *(const float4*)(vp_ + 4); \
        vr2 = *(const float4*)(vp_ + D_DIM); vr3 = *(const float4*)(vp_ + D_DIM + 4); \
    } while (0)

#define STAGE(KB, VB) do {                                                    \
        short* kd_ = (KB) + skv * KSTR + sd;                                  \
        *(uint2*)(kd_)      = make_uint2(pk2(kr0.x, kr0.y), pk2(kr0.z, kr0.w)); \
        *(uint2*)(kd_ + 4)  = make_uint2(pk2(kr1.x, kr1.y), pk2(kr1.z, kr1.w)); \
        *(uint2*)(kd_ + 8)  = make_uint2(pk2(kr2.x, kr2.y), pk2(kr2.z, kr2.w)); \
        *(uint2*)(kd_ + 12) = make_uint2(pk2(kr3.x, kr3.y), pk2(kr3.z, kr3.w)); \
        short* vd_ = (VB) + vkvp;                                             \
        *(unsigned*)(vd_ + (vdd + 0) * VSTR) = pk2(vr0.x, vr2.x);             \
        *(unsigned*)(vd_ + (vdd + 1) * VSTR) = pk2(vr0.y, vr2.y);             \
        *(unsigned*)(vd_ + (vdd + 2) * VSTR) = pk2(vr0.z, vr2.z);             \
        *(unsigned*)(vd_ + (vdd + 3) * VSTR) = pk2(vr0.w, vr2.w);             \
        *(unsigned*)(vd_ + (vdd + 4) * VSTR) = pk2(vr1.x, vr3.x);             \
        *(unsigned*)(vd_ + (vdd + 5) * VSTR) = pk2(vr1.y, vr3.y);             \
        *(unsigned*)(vd_ + (vdd + 6) * VSTR) = pk2(vr1.z, vr3.z);             \
        *(unsigned*)(vd_ + (vdd + 7) * VSTR) = pk2(vr1.w, vr3.w);             \
    } while (0)

    int q0     = q0b;
    int ntiles = ntb;

    #pragma unroll 1
    for (int sub = 0; sub < 2; ++sub) {
        // ---- Q fragments for this q-tile, PRE-SCALED by SC_LOG2E ----
        bf16x8 aq0, aq1;
        {
            const float* qp = Qh + (size_t)(q0 + wid * 16 + lcol) * D_DIM;
            float4 a = *(const float4*)(qp + quad * 8);
            float4 b = *(const float4*)(qp + quad * 8 + 4);
            float4 c = *(const float4*)(qp + 32 + quad * 8);
            float4 d = *(const float4*)(qp + 32 + quad * 8 + 4);
            aq0 = mk8(pk2(a.x * SC_LOG2E, a.y * SC_LOG2E), pk2(a.z * SC_LOG2E, a.w * SC_LOG2E),
                      pk2(b.x * SC_LOG2E, b.y * SC_LOG2E), pk2(b.z * SC_LOG2E, b.w * SC_LOG2E));
            aq1 = mk8(pk2(c.x * SC_LOG2E, c.y * SC_LOG2E), pk2(c.z * SC_LOG2E, c.w * SC_LOG2E),
                      pk2(d.x * SC_LOG2E, d.y * SC_LOG2E), pk2(d.z * SC_LOG2E, d.w * SC_LOG2E));
        }

        f32x4 o[4];
        #pragma unroll
        for (int nt = 0; nt < 4; ++nt) o[nt] = f32x4{0.f, 0.f, 0.f, 0.f};
        float lp = 0.f;

        // prologue: stage tile 0, issue prefetch of tile 1
        PREFETCH(0);
        STAGE(Kl[0], Vt[0]);
        if (ntiles > 1) PREFETCH(1);
        __syncthreads();

        for (int tile = 0; tile < ntiles; ++tile) {
            const int cur = tile & 1;
            const short* Kb = Kl[cur];
            const short* Vb = Vt[cur];
            const bool diag = (tile == ntiles - 1);

            // ---- stage NEXT tile first (prev barrier made cur^1 safe);
            //      ds_writes overlap MFMA compute below; then prefetch t+2 ----
            if (tile + 1 < ntiles) {
                STAGE(Kl[cur ^ 1], Vt[cur ^ 1]);
                if (tile + 2 < ntiles) PREFETCH(tile + 2);
            }

            // ---- FUSED swapped QK^T + softmax, per-ct: scores live 4 regs
            //      at a time; exp packed straight into PV A-fragment words.
            //      lane holds e[ct][r] = P[q=lcol][16ct+4quad+r]; A-frag slot
            //      (h,j) needs P[q][pi(32h+8quad+j)] = e[2h+(j>>2)][j&3]. ----
            unsigned pb[8];
            __builtin_amdgcn_s_setprio(1);
            #pragma unroll
            for (int ct = 0; ct < 4; ++ct) {
                const short* kp0 = &Kb[(ct * 16 + lcol) * KSTR + quad * 8];
                const bf16x8 b0 = ldfrag(kp0);        // d = quad*8+j
                const bf16x8 b1 = ldfrag(kp0 + 32);   // d = 32+quad*8+j
                f32x4 z = f32x4{0.f, 0.f, 0.f, 0.f};
                z = __builtin_amdgcn_mfma_f32_16x16x32_bf16(b0, aq0, z, 0, 0, 0);
                z = __builtin_amdgcn_mfma_f32_16x16x32_bf16(b1, aq1, z, 0, 0, 0);
                float e_[4];
                #pragma unroll
                for (int r = 0; r < 4; ++r) {
                    float x = z[r];
                    if (diag && (ct * 16 + quad * 4 + r > qrel)) x = -__builtin_inff();
                    e_[r] = __builtin_amdgcn_exp2f(x);
                }
                lp += (e_[0] + e_[1]) + (e_[2] + e_[3]);   // tree, short chain
                pb[2 * ct]     = pk2(e_[0], e_[1]);
                pb[2 * ct + 1] = pk2(e_[2], e_[3]);
            }
            const bf16x8 ap0 = mk8(pb[0], pb[1], pb[2], pb[3]);
            const bf16x8 ap1 = mk8(pb[4], pb[5], pb[6], pb[7]);

            // ---- O += P V (sigma kv-slot order) ----
            #pragma unroll
            for (int nt = 0; nt < 4; ++nt) {
                const short* vp0 = &Vb[(nt * 16 + lcol) * VSTR + quad * 8];
                const bf16x8 v0 = ldfrag(vp0);
                const bf16x8 v1 = ldfrag(vp0 + 32);
                o[nt] = __builtin_amdgcn_mfma_f32_16x16x32_bf16(ap0, v0, o[nt], 0, 0, 0);
                o[nt] = __builtin_amdgcn_mfma_f32_16x16x32_bf16(ap1, v1, o[nt], 0, 0, 0);
            }
            __builtin_amdgcn_s_setprio(0);

            __syncthreads();
        }

        // ---- epilogue: l per-lane for q=lcol; reduce across quads only ----
        lp += __shfl_xor(lp, 16, 64);
        lp += __shfl_xor(lp, 32, 64);
        #pragma unroll
        for (int r = 0; r < 4; ++r) {
            // O rows this lane stores are q = row_l + r; their l is held by
            // lane with lcol = quad*4+r (any quad after the reduce)
            const float inv = 1.0f / __shfl(lp, quad * 4 + r, 64);
            float* op = Oh + (size_t)(q0 + row_l + r) * D_DIM;
            #pragma unroll
            for (int nt = 0; nt < 4; ++nt)
                op[nt * 16 + lcol] = o[nt][r] * inv;
        }

        // switch to the short tile (A) for the second pass
        q0     = q0a;
        ntiles = nta;
    }
}

extern "C" void kernel_launch(void* const* d_in, const int* in_sizes, int n_in,
                              void* d_out, int out_size, void* d_ws, size_t ws_size,
                              hipStream_t stream) {
    const float* Q = (const float*)d_in[0];
    const float* K = (const float*)d_in[1];
    const float* V = (const float*)d_in[2];
    float*       O = (float*)d_out;
    dim3 grid(1024);   // 16 complementary q-pairs x 64 heads, XCD-swizzled
    fattn_kernel<<<grid, 256, 0, stream>>>(Q, K, V, O);
}

// Round 6
// 173.783 us; speedup vs baseline: 2.0463x; 1.3395x over previous
//
#include <hip/hip_runtime.h>

// Causal flash attention fwd: B=4,H=16,S=2048,D=64. fp32 I/O, bf16 MFMA compute.
// R10: 32x32x16 MFMA restructure. R6-R9 showed the 16x16 / 64q-per-block
// structure is overhead-bound (all pipes <25%) and sits exactly at the
// (256,4) 128-reg cliff (every variant either spilled or starved occupancy).
// New shape: each wave owns 32 q-rows via mfma_f32_32x32x16_bf16 -> block =
// 128 q-rows; same staging + same frag-read count now serve 2x FLOP. R7's
// concurrent complementary pair restored (shared K/V frags + shared staging):
// per head staged 64x64 units drop 528 -> 200. Register problem solved by
// grid sizing: 64 heads x 8 pairs = 512 blocks = exactly 2/CU, so
// launch_bounds(256,2) grants 256 regs/wave (peak ~210, spill-PROOF).
// Anti-correlated mapping (round0 heavy ip0-3, round1 light) makes each CU's
// two blocks sum to a uniform 50 units.
// MFMA 32x32x16 layouts (C/D HW-verified m74/m101; A/B by family):
//   A[m=lane&31][k=8*(lane>>5)+j], B[k=8*(lane>>5)+j][n=lane&31],
//   C/D: col=lane&31, row=(reg&3)+8*(reg>>2)+4*(lane>>5).
// Swapped QK^T (S^T = mfma(K,Q)): lane holds P[q=lane&31][kv: kv%8 in
// [4h,4h+4)]. V kv-slot order sigma(16s+8h+j)=32(s>>1)+8(2(s&1)+(j>>2))+
// (j&3)+4h makes PV A-frag pa[s] = pk2 of CONSECUTIVE C/D regs
// (e_T[8(s&1)+2k], e_T[8(s&1)+2k+1]), T=s>>1: P never leaves the lane.
// V staged transposed [d][sigma^-1(kv)] (free constant addr shuffle).
// Retained: pre-scaled Q (SC_LOG2E folded), raw-float4 prefetch with
// pack-in-STAGE at iteration start (full-iter latency cover), double-buffered
// K/V LDS, ONE barrier/unit, T5 setprio, per-tile fused softmax.

typedef short bf16x4 __attribute__((ext_vector_type(4)));
typedef short bf16x8 __attribute__((ext_vector_type(8)));
typedef float f32x16 __attribute__((ext_vector_type(16)));

#define S_LEN 2048
#define D_DIM 64
#define KVB 64
#define KSTR 68
#define VSTR 68
#define SC_LOG2E 0.18033688011112042f   // (1/8) * log2(e), folded into Q frags

// pack two fp32 -> bf16x2 dword by truncation (1 v_perm_b32)
__device__ __forceinline__ unsigned pk2(float lo, float hi) {
    return __builtin_amdgcn_perm(__builtin_bit_cast(unsigned, hi),
                                 __builtin_bit_cast(unsigned, lo), 0x07060302u);
}

__device__ __forceinline__ bf16x8 ldfrag(const short* p) {
    bf16x4 lo = *(const bf16x4*)(p);
    bf16x4 hi = *(const bf16x4*)(p + 4);
    bf16x8 r;
    r[0] = lo[0]; r[1] = lo[1]; r[2] = lo[2]; r[3] = lo[3];
    r[4] = hi[0]; r[5] = hi[1]; r[6] = hi[2]; r[7] = hi[3];
    return r;
}

__device__ __forceinline__ bf16x8 mk8(unsigned u0, unsigned u1, unsigned u2, unsigned u3) {
    union { unsigned u[4]; bf16x8 v; } r;
    r.u[0] = u0; r.u[1] = u1; r.u[2] = u2; r.u[3] = u3;
    return r.v;
}

__device__ __forceinline__ f32x16 zero16() {
    return f32x16{0.f,0.f,0.f,0.f,0.f,0.f,0.f,0.f,
                  0.f,0.f,0.f,0.f,0.f,0.f,0.f,0.f};
}

__global__ __launch_bounds__(256, 2) void fattn_kernel(
    const float* __restrict__ Q, const float* __restrict__ K,
    const float* __restrict__ V, float* __restrict__ O)
{
    __shared__ short Kl[2][KVB * KSTR];       // 17408 B  [kv][d]
    __shared__ short Vt[2][D_DIM * VSTR];     // 17408 B  [d][sigma^-1(kv)]

    const int t    = threadIdx.x;
    const int wid  = t >> 6;
    const int lane = t & 63;
    const int h    = lane >> 5;               // MFMA half
    const int l31  = lane & 31;

    // ---- block mapping: 512 blocks = 2 rounds x 8 XCD x 8 heads x 4 slots.
    //      round 0 -> ip = slot (heavy: 32-2ip units), round 1 -> ip = 7-slot
    //      (light) so each CU's two blocks sum to 50 units. ----
    const int flat  = blockIdx.x;             // 0..511
    const int halfg = flat >> 8;
    const int r     = flat & 255;
    const int xcd   = r & 7;
    const int rr    = r >> 3;                 // 0..31
    const int bh    = xcd * 8 + (rr & 7);     // head 0..63
    const int slot  = rr >> 3;                // 0..3
    const int ip    = halfg ? (7 - slot) : slot;   // pair 0..7

    // complementary 128-row q-subblocks: B = long (idx 15-ip), A = short (ip)
    const int ntb = 32 - 2 * ip;              // kv units for B (18..32)
    const int nta = 2 * ip + 2;               // kv units for A (2..16)
    const int q0b = (15 - ip) * 128;
    const int q0a = ip * 128;

    const size_t base = (size_t)bh * (S_LEN * D_DIM);
    const float* Qh = Q + base;
    const float* Kh = K + base;
    const float* Vh = V + base;
    float*       Oh = O + base;

    // staging coordinates
    const int skv = t >> 2;                   // K: row 0..63
    const int sd  = (t & 3) * 16;             // K: 16-col block
    const int vkv = (t & 31) * 2;             // V: row pair (even)
    const int vdd = (t >> 5) * 8;             // V: 8-col block
    // vslot = sigma^-1(vkv): kv = 32T+8m+t'+4h' -> p = 32T+16(m>>1)+8h'+4(m&1)+t'
    const int sT = vkv >> 5, sm = (vkv >> 3) & 3, sh = (vkv >> 2) & 1, st = vkv & 3;
    const int vslot = 32 * sT + 16 * (sm >> 1) + 8 * sh + 4 * (sm & 1) + st;

    // ---- Q fragments (B-operand), PRE-SCALED by SC_LOG2E.
    //      lane supplies q-col = q0x + 32*wid + l31, d = 16s + 8h + j ----
    bf16x8 aqB[4], aqA[4];
    {
        const float* qp = Qh + (size_t)(q0b + 32 * wid + l31) * D_DIM;
        #pragma unroll
        for (int s = 0; s < 4; ++s) {
            const int d0 = 16 * s + 8 * h;
            float4 a = *(const float4*)(qp + d0);
            float4 b = *(const float4*)(qp + d0 + 4);
            aqB[s] = mk8(pk2(a.x * SC_LOG2E, a.y * SC_LOG2E),
                         pk2(a.z * SC_LOG2E, a.w * SC_LOG2E),
                         pk2(b.x * SC_LOG2E, b.y * SC_LOG2E),
                         pk2(b.z * SC_LOG2E, b.w * SC_LOG2E));
        }
    }
    {
        const float* qp = Qh + (size_t)(q0a + 32 * wid + l31) * D_DIM;
        #pragma unroll
        for (int s = 0; s < 4; ++s) {
            const int d0 = 16 * s + 8 * h;
            float4 a = *(const float4*)(qp + d0);
            float4 b = *(const float4*)(qp + d0 + 4);
            aqA[s] = mk8(pk2(a.x * SC_LOG2E, a.y * SC_LOG2E),
                         pk2(a.z * SC_LOG2E, a.w * SC_LOG2E),
                         pk2(b.x * SC_LOG2E, b.y * SC_LOG2E),
                         pk2(b.z * SC_LOG2E, b.w * SC_LOG2E));
        }
    }

    f32x16 oB[2], oA[2];
    oB[0] = zero16(); oB[1] = zero16();
    oA[0] = zero16(); oA[1] = zero16();
    float lpB = 0.f, lpA = 0.f;
    const int qBl = q0b + 32 * wid + l31;     // this lane's q (softmax col)
    const int qAl = q0a + 32 * wid + l31;

    // prefetch registers: RAW float4, packed only inside STAGE one iteration
    // after issue -> full iteration of global-latency cover
    float4 kr0, kr1, kr2, kr3, vr0, vr1, vr2, vr3;

#define PREFETCH(tl) do {                                                     \
        const float* kp_ = Kh + (size_t)((tl) * KVB + skv) * D_DIM + sd;      \
        kr0 = *(const float4*)(kp_);     kr1 = *(const float4*)(kp_ + 4);     \
        kr2 = *(const float4*)(kp_ + 8); kr3 = *(const float4*)(kp_ + 12);    \
        const float* vp_ = Vh + (size_t)((tl) * KVB + vkv) * D_DIM + vdd;     \
        vr0 = *(const float4*)(vp_);         vr1 = *(const float4*)(vp_ + 4); \
        vr2 = *(const float4*)(vp_ + D_DIM); vr3 = *(const float4*)(vp_ + D_DIM + 4); \
    } while (0)

#define STAGE(KB, VB) do {                                                    \
        short* kd_ = (KB) + skv * KSTR + sd;                                  \
        *(uint2*)(kd_)      = make_uint2(pk2(kr0.x, kr0.y), pk2(kr0.z, kr0.w)); \
        *(uint2*)(kd_ + 4)  = make_uint2(pk2(kr1.x, kr1.y), pk2(kr1.z, kr1.w)); \
        *(uint2*)(kd_ + 8)  = make_uint2(pk2(kr2.x, kr2.y), pk2(kr2.z, kr2.w)); \
        *(uint2*)(kd_ + 12) = make_uint2(pk2(kr3.x, kr3.y), pk2(kr3.z, kr3.w)); \
        short* vd_ = (VB) + vslot;                                            \
        *(unsigned*)(vd_ + (vdd + 0) * VSTR) = pk2(vr0.x, vr2.x);             \
        *(unsigned*)(vd_ + (vdd + 1) * VSTR) = pk2(vr0.y, vr2.y);             \
        *(unsigned*)(vd_ + (vdd + 2) * VSTR) = pk2(vr0.z, vr2.z);             \
        *(unsigned*)(vd_ + (vdd + 3) * VSTR) = pk2(vr0.w, vr2.w);             \
        *(unsigned*)(vd_ + (vdd + 4) * VSTR) = pk2(vr1.x, vr3.x);             \
        *(unsigned*)(vd_ + (vdd + 5) * VSTR) = pk2(vr1.y, vr3.y);             \
        *(unsigned*)(vd_ + (vdd + 6) * VSTR) = pk2(vr1.z, vr3.z);             \
        *(unsigned*)(vd_ + (vdd + 7) * VSTR) = pk2(vr1.w, vr3.w);             \
    } while (0)

    // prologue
    PREFETCH(0);
    STAGE(Kl[0], Vt[0]);
    if (ntb > 1) PREFETCH(1);
    __syncthreads();

    #pragma unroll 1
    for (int kt = 0; kt < ntb; ++kt) {
        const int cur = kt & 1;
        const short* Kb = Kl[cur];
        const short* Vb = Vt[cur];
        const bool doA = (kt < nta);

        // stage NEXT unit first (prev barrier made cur^1 safe); ds_writes
        // overlap the MFMAs below; then issue global prefetch for kt+2
        if (kt + 1 < ntb) {
            STAGE(Kl[cur ^ 1], Vt[cur ^ 1]);
            if (kt + 2 < ntb) PREFETCH(kt + 2);
        }

        unsigned pbB[16], pbA[16];
        __builtin_amdgcn_s_setprio(1);

        // ---- swapped QK^T + fused softmax, per kv-half T (32 rows each).
        //      K A-frags shared between B and A subblocks. ----
        #pragma unroll
        for (int T = 0; T < 2; ++T) {
            const short* kp = &Kb[(32 * T + l31) * KSTR + 8 * h];
            const bf16x8 kf0 = ldfrag(kp);
            const bf16x8 kf1 = ldfrag(kp + 16);
            const bf16x8 kf2 = ldfrag(kp + 32);
            const bf16x8 kf3 = ldfrag(kp + 48);
            const int kvb = 64 * kt + 32 * T;

            {
                f32x16 z = zero16();
                z = __builtin_amdgcn_mfma_f32_32x32x16_bf16(kf0, aqB[0], z, 0, 0, 0);
                z = __builtin_amdgcn_mfma_f32_32x32x16_bf16(kf1, aqB[1], z, 0, 0, 0);
                z = __builtin_amdgcn_mfma_f32_32x32x16_bf16(kf2, aqB[2], z, 0, 0, 0);
                z = __builtin_amdgcn_mfma_f32_32x32x16_bf16(kf3, aqB[3], z, 0, 0, 0);
                const bool mB = (64 * kt + 63 > q0b + 32 * wid);
                float e[16];
                #pragma unroll
                for (int rg = 0; rg < 16; ++rg) {
                    float x = z[rg];
                    if (mB && (kvb + (rg & 3) + 8 * (rg >> 2) + 4 * h > qBl))
                        x = -__builtin_inff();
                    e[rg] = __builtin_amdgcn_exp2f(x);
                }
                lpB += (((e[0]+e[1])+(e[2]+e[3])) + ((e[4]+e[5])+(e[6]+e[7])))
                     + (((e[8]+e[9])+(e[10]+e[11])) + ((e[12]+e[13])+(e[14]+e[15])));
                #pragma unroll
                for (int k2 = 0; k2 < 8; ++k2)
                    pbB[8 * T + k2] = pk2(e[2 * k2], e[2 * k2 + 1]);
            }
            if (doA) {
                f32x16 z = zero16();
                z = __builtin_amdgcn_mfma_f32_32x32x16_bf16(kf0, aqA[0], z, 0, 0, 0);
                z = __builtin_amdgcn_mfma_f32_32x32x16_bf16(kf1, aqA[1], z, 0, 0, 0);
                z = __builtin_amdgcn_mfma_f32_32x32x16_bf16(kf2, aqA[2], z, 0, 0, 0);
                z = __builtin_amdgcn_mfma_f32_32x32x16_bf16(kf3, aqA[3], z, 0, 0, 0);
                const bool mA = (64 * kt + 63 > q0a + 32 * wid);
                float e[16];
                #pragma unroll
                for (int rg = 0; rg < 16; ++rg) {
                    float x = z[rg];
                    if (mA && (kvb + (rg & 3) + 8 * (rg >> 2) + 4 * h > qAl))
                        x = -__builtin_inff();
                    e[rg] = __builtin_amdgcn_exp2f(x);
                }
                lpA += (((e[0]+e[1])+(e[2]+e[3])) + ((e[4]+e[5])+(e[6]+e[7])))
                     + (((e[8]+e[9])+(e[10]+e[11])) + ((e[12]+e[13])+(e[14]+e[15])));
                #pragma unroll
                for (int k2 = 0; k2 < 8; ++k2)
                    pbA[8 * T + k2] = pk2(e[2 * k2], e[2 * k2 + 1]);
            }
        }

        // ---- PV: O += P V. pa[s] = pb[4s..4s+3] (in-lane, sigma slot order);
        //      V B-frags shared between B and A. ----
        #pragma unroll
        for (int DT = 0; DT < 2; ++DT) {
            const short* vp = &Vb[(32 * DT + l31) * VSTR + 8 * h];
            #pragma unroll
            for (int s = 0; s < 4; ++s) {
                const bf16x8 vf = ldfrag(vp + 16 * s);
                const bf16x8 pfB = mk8(pbB[4*s], pbB[4*s+1], pbB[4*s+2], pbB[4*s+3]);
                oB[DT] = __builtin_amdgcn_mfma_f32_32x32x16_bf16(pfB, vf, oB[DT], 0, 0, 0);
                if (doA) {
                    const bf16x8 pfA = mk8(pbA[4*s], pbA[4*s+1], pbA[4*s+2], pbA[4*s+3]);
                    oA[DT] = __builtin_amdgcn_mfma_f32_32x32x16_bf16(pfA, vf, oA[DT], 0, 0, 0);
                }
            }
        }
        __builtin_amdgcn_s_setprio(0);

        __syncthreads();
    }

    // ---- epilogue: lane holds half-row sum for q = l31; combine halves,
    //      then per-output-row l via shfl from lane qrow ----
    lpB += __shfl_xor(lpB, 32, 64);
    lpA += __shfl_xor(lpA, 32, 64);
    #pragma unroll
    for (int rg = 0; rg < 16; ++rg) {
        const int qrow = (rg & 3) + 8 * (rg >> 2) + 4 * h;
        const float invB = 1.0f / __shfl(lpB, qrow, 64);
        const float invA = 1.0f / __shfl(lpA, qrow, 64);
        float* opB = Oh + (size_t)(q0b + 32 * wid + qrow) * D_DIM + l31;
        float* opA = Oh + (size_t)(q0a + 32 * wid + qrow) * D_DIM + l31;
        opB[0]  = oB[0][rg] * invB;
        opB[32] = oB[1][rg] * invB;
        opA[0]  = oA[0][rg] * invA;
        opA[32] = oA[1][rg] * invA;
    }
}

extern "C" void kernel_launch(void* const* d_in, const int* in_sizes, int n_in,
                              void* d_out, int out_size, void* d_ws, size_t ws_size,
                              hipStream_t stream) {
    const float* Q = (const float*)d_in[0];
    const float* K = (const float*)d_in[1];
    const float* V = (const float*)d_in[2];
    float*       O = (float*)d_out;
    dim3 grid(512);   // 64 heads x 8 pairs x 2 balance-rounds, XCD-clustered
    fattn_kernel<<<grid, 256, 0, stream>>>(Q, K, V, O);
}

// Round 8
// 170.390 us; speedup vs baseline: 2.0870x; 1.0199x over previous
//
#include <hip/hip_runtime.h>

// Causal flash attention fwd: B=4,H=16,S=2048,D=64. fp32 I/O, bf16 MFMA compute.
// R11 (resubmit; round 7 was an infra failure, kernel unchanged after audit):
// 512-thread single-supertile blocks. R10 (verified spill-free, 84us) was
// capped at 8 waves/CU: 2 blocks x 4 waves at 192 regs, grid-limited. New
// shape: block = 8 waves x 32 q-rows = ONE 256-row q-supertile; grid = 64
// heads x 8 supertiles = 512 blocks = 2/CU -> 16 waves/CU (4/SIMD), 2x
// latency hiding, IF regs <= 128 (launch_bounds(512,4)). Single-subblock
// structure fits: o=32 AGPR, aq=16, pb=8 (PV split per-T), prefetch=8 (K/V
// prefetch time-split), transients ~32 -> ~117. Staging per thread HALVES
// (512 threads/tile), each tile serves 256q always -> stagings/head 200->144.
// Anti-correlated dispatch (j vs 7-j per CU) keeps per-CU work uniform (36
// units). Triangle-aware wave skip: wave w active only kt <= 4j+(w>>1)
// (fully-masked units skipped; up to 37% compute saved on low-j blocks).
// Diag masking reduces to const-idx compare (idx+4h > l31); even-wid waves
// skip the all-masked T=1 half on their diag unit.
// MFMA 32x32x16 layouts (C/D HW-verified m74/m101, R10 end-to-end verified):
//   A[m=lane&31][k=8*(lane>>5)+j], B[k=8*(lane>>5)+j][n=lane&31],
//   C/D: col=lane&31, row=(reg&3)+8*(reg>>2)+4*(lane>>5).
// Swapped QK^T (S^T = mfma(K,Q)); V kv-slot order sigma(16s+8h+j) =
// 32(s>>1)+8(2(s&1)+(j>>2))+(j&3)+4h -> PV A-frag = pk2 of consecutive C/D
// regs, P never leaves the lane. V staged transposed [d][sigma^-1(kv)].
// Retained: pre-scaled Q (SC_LOG2E folded), raw-fp32 prefetch packed in
// STAGE one unit after issue, double-buffered K/V LDS, ONE barrier/unit,
// T5 setprio.

typedef short bf16x4 __attribute__((ext_vector_type(4)));
typedef short bf16x8 __attribute__((ext_vector_type(8)));
typedef float f32x16 __attribute__((ext_vector_type(16)));

#define S_LEN 2048
#define D_DIM 64
#define KVB 64
#define KSTR 68
#define VSTR 68
#define SC_LOG2E 0.18033688011112042f   // (1/8) * log2(e), folded into Q frags

__device__ __forceinline__ unsigned pk2(float lo, float hi) {
    return __builtin_amdgcn_perm(__builtin_bit_cast(unsigned, hi),
                                 __builtin_bit_cast(unsigned, lo), 0x07060302u);
}

__device__ __forceinline__ bf16x8 ldfrag(const short* p) {
    bf16x4 lo = *(const bf16x4*)(p);
    bf16x4 hi = *(const bf16x4*)(p + 4);
    bf16x8 r;
    r[0] = lo[0]; r[1] = lo[1]; r[2] = lo[2]; r[3] = lo[3];
    r[4] = hi[0]; r[5] = hi[1]; r[6] = hi[2]; r[7] = hi[3];
    return r;
}

__device__ __forceinline__ bf16x8 mk8(unsigned u0, unsigned u1, unsigned u2, unsigned u3) {
    union { unsigned u[4]; bf16x8 v; } r;
    r.u[0] = u0; r.u[1] = u1; r.u[2] = u2; r.u[3] = u3;
    return r.v;
}

__device__ __forceinline__ f32x16 zero16() {
    return f32x16{0.f,0.f,0.f,0.f,0.f,0.f,0.f,0.f,
                  0.f,0.f,0.f,0.f,0.f,0.f,0.f,0.f};
}

__global__ __launch_bounds__(512, 4) void fattn_kernel(
    const float* __restrict__ Q, const float* __restrict__ K,
    const float* __restrict__ V, float* __restrict__ O)
{
    __shared__ short Kl[2][KVB * KSTR];       // 17408 B  [kv][d]
    __shared__ short Vt[2][D_DIM * VSTR];     // 17408 B  [d][sigma^-1(kv)]

    const int t    = threadIdx.x;
    const int wid  = t >> 6;                  // 0..7
    const int lane = t & 63;
    const int h    = lane >> 5;
    const int l31  = lane & 31;

    // ---- dispatch: 2 rounds x (8 xcd x 8 heads x 4 slots). Round 0 gets
    //      j = slot (light 0..3), round 1 gets j = 7-slot (heavy) -> each CU
    //      hosts pair (j, 7-j): 4(j+1) + 4(8-j) = 36 units uniform. ----
    const int flat  = blockIdx.x;             // 0..511
    const int round = flat >> 8;
    const int r     = flat & 255;
    const int xcd   = r & 7;
    const int rr    = r >> 3;                 // 0..31
    const int bh    = xcd * 8 + (rr & 7);     // head 0..63
    const int slot  = rr >> 3;                // 0..3
    const int j     = round ? (7 - slot) : slot;

    const int q0     = j * 256;
    const int nt     = 4 * (j + 1);           // kv units for this supertile
    const int qbase  = q0 + 32 * wid;         // this wave's 32 q-rows
    const int ktlast = 4 * j + (wid >> 1);    // last unit with any visible kv

    const size_t base = (size_t)bh * (S_LEN * D_DIM);
    const float* Qh = Q + base;
    const float* Kh = K + base;
    const float* Vh = V + base;
    float*       Oh = O + base;

    // staging coordinates (512 threads share one 64x64 tile: 8 elems each)
    const int skv = t >> 3;                   // K row 0..63
    const int sd  = (t & 7) * 8;              // K 8-col block
    const int vkv = (t & 31) * 2;             // V row pair (even)
    const int vdd = (t >> 5) * 4;             // V 4-col block (0..60)
    // vslot = sigma^-1(vkv)
    const int sT = vkv >> 5, sm = (vkv >> 3) & 3, sh = (vkv >> 2) & 1, st = vkv & 3;
    const int vslot = 32 * sT + 16 * (sm >> 1) + 8 * sh + 4 * (sm & 1) + st;

    // ---- Q fragments (B-operand), PRE-SCALED by SC_LOG2E ----
    bf16x8 aq[4];
    {
        const float* qp = Qh + (size_t)(qbase + l31) * D_DIM;
        #pragma unroll
        for (int s = 0; s < 4; ++s) {
            const int d0 = 16 * s + 8 * h;
            float4 a = *(const float4*)(qp + d0);
            float4 b = *(const float4*)(qp + d0 + 4);
            aq[s] = mk8(pk2(a.x * SC_LOG2E, a.y * SC_LOG2E),
                        pk2(a.z * SC_LOG2E, a.w * SC_LOG2E),
                        pk2(b.x * SC_LOG2E, b.y * SC_LOG2E),
                        pk2(b.z * SC_LOG2E, b.w * SC_LOG2E));
        }
    }

    f32x16 o0 = zero16(), o1 = zero16();
    float lpx0 = 0.f, lpx1 = 0.f;
    const int thr = l31 - 4 * h;              // mask: const idx > thr

    float4 kr0, kr1, vr0, vr1;                // raw fp32 prefetch (time-split)

#define PREFK(tl) do {                                                        \
        const float* kp_ = Kh + (size_t)((tl) * KVB + skv) * D_DIM + sd;      \
        kr0 = *(const float4*)(kp_); kr1 = *(const float4*)(kp_ + 4);         \
    } while (0)
#define PREFV(tl) do {                                                        \
        const float* vp_ = Vh + (size_t)((tl) * KVB + vkv) * D_DIM + vdd;     \
        vr0 = *(const float4*)(vp_); vr1 = *(const float4*)(vp_ + D_DIM);     \
    } while (0)
#define STAGEK(KB) do {                                                       \
        short* kd_ = (KB) + skv * KSTR + sd;                                  \
        *(uint2*)(kd_)     = make_uint2(pk2(kr0.x, kr0.y), pk2(kr0.z, kr0.w));\
        *(uint2*)(kd_ + 4) = make_uint2(pk2(kr1.x, kr1.y), pk2(kr1.z, kr1.w));\
    } while (0)
#define STAGEV(VB) do {                                                       \
        short* vd_ = (VB) + vslot;                                            \
        *(unsigned*)(vd_ + (vdd + 0) * VSTR) = pk2(vr0.x, vr1.x);             \
        *(unsigned*)(vd_ + (vdd + 1) * VSTR) = pk2(vr0.y, vr1.y);             \
        *(unsigned*)(vd_ + (vdd + 2) * VSTR) = pk2(vr0.z, vr1.z);             \
        *(unsigned*)(vd_ + (vdd + 3) * VSTR) = pk2(vr0.w, vr1.w);             \
    } while (0)

// QK half-T: 4-MFMA chain into z, mask (const idx), exp2, pack pb[0..7], lp
#define QK_EXP_T(Tofs, msk) do {                                              \
        const short* kp_ = &Kb[((Tofs) + l31) * KSTR + 8 * h];                \
        const bf16x8 kf0 = ldfrag(kp_);                                       \
        const bf16x8 kf1 = ldfrag(kp_ + 16);                                  \
        const bf16x8 kf2 = ldfrag(kp_ + 32);                                  \
        const bf16x8 kf3 = ldfrag(kp_ + 48);                                  \
        f32x16 z = zero16();                                                  \
        z = __builtin_amdgcn_mfma_f32_32x32x16_bf16(kf0, aq[0], z, 0, 0, 0);  \
        z = __builtin_amdgcn_mfma_f32_32x32x16_bf16(kf1, aq[1], z, 0, 0, 0);  \
        z = __builtin_amdgcn_mfma_f32_32x32x16_bf16(kf2, aq[2], z, 0, 0, 0);  \
        z = __builtin_amdgcn_mfma_f32_32x32x16_bf16(kf3, aq[3], z, 0, 0, 0);  \
        _Pragma("unroll")                                                     \
        for (int k2 = 0; k2 < 8; ++k2) {                                      \
            const int i0 = ((2*k2) & 3) + 8 * ((2*k2) >> 2);                  \
            float x0 = z[2*k2], x1 = z[2*k2+1];                               \
            if (msk) {                                                        \
                if (i0 > thr)     x0 = -__builtin_inff();                     \
                if (i0 + 1 > thr) x1 = -__builtin_inff();                     \
            }                                                                 \
            const float e0 = __builtin_amdgcn_exp2f(x0);                      \
            const float e1 = __builtin_amdgcn_exp2f(x1);                      \
            if (k2 < 4) lpx0 += e0 + e1; else lpx1 += e0 + e1;                \
            pb[k2] = pk2(e0, e1);                                             \
        }                                                                     \
    } while (0)

// PV for two sigma-slots sg (s = sbase+sg): o0/o1 chains interleaved
#define PV2(sbase) do {                                                       \
        _Pragma("unroll")                                                     \
        for (int sg = 0; sg < 2; ++sg) {                                      \
            const int co = 16 * ((sbase) + sg) + 8 * h;                       \
            const bf16x8 pf = mk8(pb[4*sg], pb[4*sg+1], pb[4*sg+2], pb[4*sg+3]); \
            const bf16x8 vf0 = ldfrag(&Vb[l31 * VSTR + co]);                  \
            const bf16x8 vf1 = ldfrag(&Vb[(32 + l31) * VSTR + co]);           \
            o0 = __builtin_amdgcn_mfma_f32_32x32x16_bf16(pf, vf0, o0, 0, 0, 0); \
            o1 = __builtin_amdgcn_mfma_f32_32x32x16_bf16(pf, vf1, o1, 0, 0, 0); \
        }                                                                     \
    } while (0)

    // prologue: stage unit 0, prefetch unit 1  (nt >= 4 always)
    PREFK(0); PREFV(0);
    STAGEK(Kl[0]); STAGEV(Vt[0]);
    PREFK(1); PREFV(1);
    __syncthreads();

    #pragma unroll 1
    for (int kt = 0; kt < nt; ++kt) {
        const int cur = kt & 1;
        const short* Kb = Kl[cur];
        const short* Vb = Vt[cur];
        const bool more   = (kt + 1 < nt);
        const bool active = (kt <= ktlast);
        const bool diag   = (kt == ktlast);

        // K staging for next unit + K prefetch for unit+2 (issued early;
        // consumed a full unit later)
        if (more) STAGEK(Kl[cur ^ 1]);
        if (kt + 2 < nt) PREFK(kt + 2);

        unsigned pb[8];
        if (active) {
            __builtin_amdgcn_s_setprio(1);
            // T=0: masked only on even-wid diag (kv base == qbase)
            QK_EXP_T(0, (diag && !(wid & 1)));
            PV2(0);
            __builtin_amdgcn_s_setprio(0);
        }

        // V staging + prefetch mid-unit (kr regs dead -> liveness minimized)
        if (more) STAGEV(Vt[cur ^ 1]);
        if (kt + 2 < nt) PREFV(kt + 2);

        if (active && !(diag && !(wid & 1))) {
            // T=1: skipped entirely on even-wid diag (fully masked);
            // masked on odd-wid diag
            __builtin_amdgcn_s_setprio(1);
            QK_EXP_T(32, (diag && (wid & 1)));
            PV2(2);
            __builtin_amdgcn_s_setprio(0);
        }

        __syncthreads();
    }

    // ---- epilogue: lane holds half-row sum for q = qbase+l31; combine
    //      halves, then per-output-row l via shfl from lane qrow ----
    float lp = lpx0 + lpx1;
    lp += __shfl_xor(lp, 32, 64);
    #pragma unroll
    for (int rg = 0; rg < 16; ++rg) {
        const int qrow = (rg & 3) + 8 * (rg >> 2) + 4 * h;
        const float inv = 1.0f / __shfl(lp, qrow, 64);
        float* op = Oh + (size_t)(qbase + qrow) * D_DIM + l31;
        op[0]  = o0[rg] * inv;
        op[32] = o1[rg] * inv;
    }
}

extern "C" void kernel_launch(void* const* d_in, const int* in_sizes, int n_in,
                              void* d_out, int out_size, void* d_ws, size_t ws_size,
                              hipStream_t stream) {
    const float* Q = (const float*)d_in[0];
    const float* K = (const float*)d_in[1];
    const float* V = (const float*)d_in[2];
    float*       O = (float*)d_out;
    dim3 grid(512);   // 64 heads x 8 supertiles x 2 anti-correlated rounds
    fattn_kernel<<<grid, 512, 0, stream>>>(Q, K, V, O);
}